// Round 5
// baseline (2619.469 us; speedup 1.0000x reference)
//
#include <hip/hip_runtime.h>

#define NB 32
#define NT 128
#define NU 768
#define ND 768
#define UPB 3          // u's per block
#define NC 16          // chunks per (u,b) row
#define CL 48          // elements per chunk
#define NBLK 512       // (NU/UPB) u-groups x 2 b-halves = 2 blocks/CU
#define NTHR 768       // UPB x 16 b x NC = 12 waves/block, 24 waves/CU

#define AGENT __HIP_MEMORY_SCOPE_AGENT

__device__ __forceinline__ float fexp2(float x) { return __builtin_amdgcn_exp2f(x); }
__device__ __forceinline__ float frcp(float x)  { return __builtin_amdgcn_rcpf(x); }

// x[B,T,D] -> xT[T,D,B]   (coalesced layout for the RNN inner loop)
__global__ void transpose_x_kernel(const float* __restrict__ x, float* __restrict__ xT) {
  __shared__ float tile[32][33];
  const int t  = blockIdx.x;
  const int d0 = blockIdx.y * 32;
  const int lo = threadIdx.x & 31;
  const int hi = threadIdx.x >> 5;
#pragma unroll
  for (int bb = hi; bb < 32; bb += 8)
    tile[bb][lo] = x[((size_t)bb * NT + t) * ND + d0 + lo];
  __syncthreads();
#pragma unroll
  for (int dd = hi; dd < 32; dd += 8)
    xT[((size_t)t * ND + d0 + dd) * NB + lo] = tile[lo][dd];
}

// h0[B,U] -> hT[U,B], zero NBLK flags
__global__ void init_h_kernel(const float* __restrict__ h0, float* __restrict__ hT,
                              unsigned int* __restrict__ flags) {
  int i = blockIdx.x * 256 + threadIdx.x;
  if (i < NU * NB) hT[i] = h0[(i & 31) * NU + (i >> 5)];
  if (i < NBLK) flags[i] = 0u;
}

// outT[T,U,B] -> out[B,T,U]
__global__ void transpose_out_kernel(const float* __restrict__ outT, float* __restrict__ out) {
  __shared__ float tile[32][33];
  const int t  = blockIdx.x;
  const int u0 = blockIdx.y * 32;
  const int lo = threadIdx.x & 31;
  const int hi = threadIdx.x >> 5;
#pragma unroll
  for (int uu = hi; uu < 32; uu += 8)
    tile[uu][lo] = outT[((size_t)t * NU + u0 + uu) * NB + lo];
  __syncthreads();
#pragma unroll
  for (int bb = hi; bb < 32; bb += 8)
    out[((size_t)bb * NT + t) * NU + u0 + lo] = tile[lo][bb];
}

__global__ void __launch_bounds__(NTHR, 6)
rnn_fused_kernel(const float* __restrict__ xT,
                 const float* __restrict__ wk,
                 const float* __restrict__ wrk,
                 const float* __restrict__ wak,
                 const float* __restrict__ wrak,
                 const float* __restrict__ bias,
                 const float* __restrict__ gpa,
                 const float* __restrict__ gpra,
                 float* hA, float* hB,
                 float* __restrict__ outT,
                 unsigned int* flags)
{
  const int tid   = threadIdx.x;
  const int uloc  = tid >> 8;        // 0..2
  const int lt    = tid & 255;
  const int b     = lt & 15;         // 0..15 within b-half
  const int c     = lt >> 4;         // 0..15 chunk
  const int d0    = c * CL;
  const int ugrp  = blockIdx.x >> 1;
  const int bhalf = blockIdx.x & 1;
  const int u     = ugrp * UPB + uloc;
  const int bg    = bhalf * 16 + b;  // global batch index

  __shared__ float2 s2a[UPB][ND];          // (ak, k)    18 KB
  __shared__ float2 s2r[UPB][ND];          // (rak, rk)  18 KB
  __shared__ float  red[UPB][6][4][16];    // 4.5 KB

#pragma unroll
  for (int j = 0; j < UPB; ++j) {
    const int ug = ugrp * UPB + j;
    s2a[j][tid] = make_float2(wak [(size_t)ug * ND + tid], wk [(size_t)ug * ND + tid]);
    s2r[j][tid] = make_float2(wrak[(size_t)ug * NU + tid], wrk[(size_t)ug * NU + tid]);
  }
  const float bias_u = bias[u];
  const float ga  = 1.0f / (1.0f + __expf(-gpa[0]));
  const float gra = 1.0f / (1.0f + __expf(-gpra[0]));
  __syncthreads();

  float* hcur  = hA;
  float* hnext = hB;
  const float LOG2E = 1.4426950408889634f;

  for (int t = 0; t < NT; ++t) {
    const float hu = __hip_atomic_load(&hcur[u * NB + bg], __ATOMIC_RELAXED, AGENT);
    const float hs = hu * LOG2E;

    // ---- input cross-attention: d in [d0, d0+48) ----
    float s_a = 0.f, n_a = 0.f, l_a = 0.f;
    {
      const float*  xp = xT + ((size_t)t * ND + d0) * NB + bg;
      const float2* wa = &s2a[uloc][d0];
#pragma unroll 8
      for (int k = 0; k < CL; ++k) {
        float2 w2 = wa[k];                 // LDS broadcast (uniform per quarter-wave)
        float  xv = xp[k * NB];            // global, 64B-coalesced per 16 lanes
        float  e  = fexp2(hs * xv * w2.x);
        float  kx = w2.y * xv;
        s_a += e; l_a += kx; n_a = fmaf(e, kx, n_a);
      }
    }
    // ---- recurrent self-attention: v in [d0, d0+48) ----
    float s_r = 0.f, n_r = 0.f, l_r = 0.f;
    {
      float*        hp = hcur + (size_t)d0 * NB + bg;
      const float2* wr = &s2r[uloc][d0];
#pragma unroll 8
      for (int k = 0; k < CL; ++k) {
        float2 w2 = wr[k];
        float  hv = __hip_atomic_load(&hp[k * NB], __ATOMIC_RELAXED, AGENT);
        float  e  = fexp2(hs * hv * w2.x);
        float  kh = w2.y * hv;
        s_r += e; l_r += kh; n_r = fmaf(e, kh, n_r);
      }
    }

    // ---- reduce 16 chunks: xor32 + xor16 within wave (4 c's), then 4 waves via LDS ----
    float v0 = s_a, v1 = n_a, v2 = l_a, v3 = s_r, v4 = n_r, v5 = l_r;
    v0 += __shfl_xor(v0, 32); v1 += __shfl_xor(v1, 32); v2 += __shfl_xor(v2, 32);
    v3 += __shfl_xor(v3, 32); v4 += __shfl_xor(v4, 32); v5 += __shfl_xor(v5, 32);
    v0 += __shfl_xor(v0, 16); v1 += __shfl_xor(v1, 16); v2 += __shfl_xor(v2, 16);
    v3 += __shfl_xor(v3, 16); v4 += __shfl_xor(v4, 16); v5 += __shfl_xor(v5, 16);
    const int w = c >> 2;                  // wave index within uloc
    if ((tid & 63) < 16) {                 // one lane per (b, wave)
      red[uloc][0][w][b] = v0; red[uloc][1][w][b] = v1; red[uloc][2][w][b] = v2;
      red[uloc][3][w][b] = v3; red[uloc][4][w][b] = v4; red[uloc][5][w][b] = v5;
    }
    __syncthreads();

    if (lt < 16) {                         // b = lt
      float r0 = red[uloc][0][0][lt] + red[uloc][0][1][lt] + red[uloc][0][2][lt] + red[uloc][0][3][lt];
      float r1 = red[uloc][1][0][lt] + red[uloc][1][1][lt] + red[uloc][1][2][lt] + red[uloc][1][3][lt];
      float r2 = red[uloc][2][0][lt] + red[uloc][2][1][lt] + red[uloc][2][2][lt] + red[uloc][2][3][lt];
      float r3 = red[uloc][3][0][lt] + red[uloc][3][1][lt] + red[uloc][3][2][lt] + red[uloc][3][3][lt];
      float r4 = red[uloc][4][0][lt] + red[uloc][4][1][lt] + red[uloc][4][2][lt] + red[uloc][4][3][lt];
      float r5 = red[uloc][5][0][lt] + red[uloc][5][1][lt] + red[uloc][5][2][lt] + red[uloc][5][3][lt];
      const int bgl = bhalf * 16 + lt;
      float hh = r2 + bias_u + ga * (r1 * frcp(r0));
      float z  = hh + r5 + gra * (r4 * frcp(r3));
      float ex = fexp2(z * 2.8853900817779268f);   // tanh(z) = 1 - 2/(e^{2z}+1)
      float o  = 1.0f - 2.0f * frcp(ex + 1.0f);
      __hip_atomic_store(&hnext[u * NB + bgl], o, __ATOMIC_RELAXED, AGENT);
      outT[((size_t)t * NU + u) * NB + bgl] = o;
    }

    if (t != NT - 1) {
      asm volatile("s_waitcnt vmcnt(0)" ::: "memory");
      __syncthreads();   // all h-stores drained before flag publication
      if (tid == 0)
        __hip_atomic_store(&flags[blockIdx.x], (unsigned)(t + 1), __ATOMIC_RELAXED, AGENT);
      if (tid < NBLK) {
        const unsigned tgt = (unsigned)(t + 1);
        while (__hip_atomic_load(&flags[tid], __ATOMIC_RELAXED, AGENT) < tgt)
          __builtin_amdgcn_s_sleep(2);
      }
      __syncthreads();
    }
    { float* tmp = hcur; hcur = hnext; hnext = tmp; }
  }
}

extern "C" void kernel_launch(void* const* d_in, const int* in_sizes, int n_in,
                              void* d_out, int out_size, void* d_ws, size_t ws_size,
                              hipStream_t stream) {
  const float* x    = (const float*)d_in[0];
  const float* h0   = (const float*)d_in[1];
  const float* wk   = (const float*)d_in[2];
  const float* wrk  = (const float*)d_in[3];
  const float* wak  = (const float*)d_in[4];
  const float* wrak = (const float*)d_in[5];
  const float* bias = (const float*)d_in[6];
  const float* gpa  = (const float*)d_in[7];
  const float* gpra = (const float*)d_in[8];
  float* out = (float*)d_out;

  float* xT   = (float*)d_ws;                       // 12.58 MB
  float* outT = xT + (size_t)NT * ND * NB;          // 12.58 MB
  float* hA   = outT + (size_t)NT * NU * NB;        // 96 KB
  float* hB   = hA + NU * NB;                       // 96 KB
  unsigned int* flags = (unsigned int*)(hB + NU * NB);

  transpose_x_kernel<<<dim3(NT, ND / 32), 256, 0, stream>>>(x, xT);
  init_h_kernel<<<(NU * NB + 255) / 256, 256, 0, stream>>>(h0, hA, flags);
  rnn_fused_kernel<<<NBLK, NTHR, 0, stream>>>(xT, wk, wrk, wak, wrak, bias, gpa, gpra,
                                              hA, hB, outT, flags);
  transpose_out_kernel<<<dim3(NT, NU / 32), 256, 0, stream>>>(outT, out);
}

// Round 6
// 1835.477 us; speedup vs baseline: 1.4271x; 1.4271x over previous
//
#include <hip/hip_runtime.h>

#define NB 32
#define NT 128
#define NU 768
#define ND 768
#define UPB 3
#define NBLK 256          // one block per CU
#define NTHR 768          // 3 u x (16 b-pairs x 16 chunks); 12 waves/CU

#define AGENT __HIP_MEMORY_SCOPE_AGENT

typedef float f32x2 __attribute__((ext_vector_type(2)));
typedef float f32x4 __attribute__((ext_vector_type(4)));

__device__ __forceinline__ float fexp2(float x) { return __builtin_amdgcn_exp2f(x); }
__device__ __forceinline__ float frcp(float x)  { return __builtin_amdgcn_rcpf(x); }
__device__ __forceinline__ int h4idx(int u, int b) { return ((u >> 2) * 32 + b) * 4 + (u & 3); }

// x[B,T,D] -> x4[t][d4][b][4]   (dwordx4-per-(d4,b) layout)
__global__ void make_x4_kernel(const float* __restrict__ x, float* __restrict__ x4) {
  const int t = blockIdx.x;        // 0..127
  const int g = blockIdx.y;        // 0..5 (32 d4's each)
  const size_t obase = ((size_t)t * 192 + g * 32) * 128;
#pragma unroll
  for (int i = 0; i < 16; ++i) {
    int o = i * 256 + threadIdx.x;          // writes contiguous
    int d4l = o >> 7, b = (o >> 2) & 31, j = o & 3;
    x4[obase + o] = x[((size_t)b * NT + t) * ND + (g * 32 + d4l) * 4 + j];
  }
}

// h0[B,U] -> h4[u4][b][4], zero flags
__global__ void init_h4_kernel(const float* __restrict__ h0, float* __restrict__ h4,
                               unsigned int* __restrict__ flags) {
  int i = blockIdx.x * 256 + threadIdx.x;
  if (i < NU * NB) {
    int u4 = i >> 7, b = (i >> 2) & 31, j = i & 3;
    h4[i] = h0[b * NU + u4 * 4 + j];
  }
  if (i < NBLK) flags[i] = 0u;
}

// outT[T,U,B] -> out[B,T,U]
__global__ void transpose_out_kernel(const float* __restrict__ outT, float* __restrict__ out) {
  __shared__ float tile[32][33];
  const int t  = blockIdx.x;
  const int u0 = blockIdx.y * 32;
  const int lo = threadIdx.x & 31;
  const int hi = threadIdx.x >> 5;
#pragma unroll
  for (int uu = hi; uu < 32; uu += 8)
    tile[uu][lo] = outT[((size_t)t * NU + u0 + uu) * NB + lo];
  __syncthreads();
#pragma unroll
  for (int bb = hi; bb < 32; bb += 8)
    out[((size_t)bb * NT + t) * NU + u0 + lo] = tile[lo][bb];
}

__global__ void __launch_bounds__(NTHR, 3)
rnn_fused_kernel(const float* __restrict__ x4,
                 const float* __restrict__ wk,
                 const float* __restrict__ wrk,
                 const float* __restrict__ wak,
                 const float* __restrict__ wrak,
                 const float* __restrict__ bias,
                 const float* __restrict__ gpa,
                 const float* __restrict__ gpra,
                 float* hA, float* hB,
                 float* __restrict__ outT,
                 unsigned int* flags)
{
  const int tid  = threadIdx.x;
  const int uloc = tid >> 8;       // 0..2
  const int lt   = tid & 255;
  const int b    = lt & 15;        // handles b and b+16
  const int c    = lt >> 4;        // 0..15 chunk of 48 d
  const int d0   = c * 48;
  const int u    = blockIdx.x * UPB + uloc;

  __shared__ __align__(16) float s_ak[UPB][ND], s_k[UPB][ND], s_rak[UPB][ND], s_rk[UPB][ND];
  __shared__ float red[UPB][12][4][16];

#pragma unroll
  for (int j = 0; j < UPB; ++j) {
    const int ug = blockIdx.x * UPB + j;
    s_ak [j][tid] = wak [(size_t)ug * ND + tid];
    s_k  [j][tid] = wk  [(size_t)ug * ND + tid];
    s_rak[j][tid] = wrak[(size_t)ug * NU + tid];
    s_rk [j][tid] = wrk [(size_t)ug * NU + tid];
  }
  const float bias_u = bias[u];
  const float ga  = 1.0f / (1.0f + __expf(-gpa[0]));
  const float gra = 1.0f / (1.0f + __expf(-gpra[0]));
  __syncthreads();

  const float* hcur = hA;
  float* hnext = hB;
  const float LOG2E = 1.4426950408889634f;

  for (int t = 0; t < NT; ++t) {
    const float huA = __hip_atomic_load(&hcur[h4idx(u, b)],      __ATOMIC_RELAXED, AGENT);
    const float huB = __hip_atomic_load(&hcur[h4idx(u, b + 16)], __ATOMIC_RELAXED, AGENT);
    const float hsA = huA * LOG2E, hsB = huB * LOG2E;
    const f32x4 hsA4 = {hsA, hsA, hsA, hsA};
    const f32x4 hsB4 = {hsB, hsB, hsB, hsB};

    f32x4 saA = {0,0,0,0}, naA = {0,0,0,0}, laA = {0,0,0,0};
    f32x4 srA = {0,0,0,0}, nrA = {0,0,0,0}, lrA = {0,0,0,0};
    f32x4 saB = {0,0,0,0}, naB = {0,0,0,0}, laB = {0,0,0,0};
    f32x4 srB = {0,0,0,0}, nrB = {0,0,0,0}, lrB = {0,0,0,0};

    const f32x4*  xp = (const f32x4*)x4 + (((size_t)t * 192 + c * 12) * 32 + b);
    const double* hq = (const double*)hcur + ((size_t)(c * 12) * 32 + b) * 2;

#pragma unroll
    for (int k4 = 0; k4 < 12; ++k4) {
      const f32x4 av  = *(const f32x4*)&s_ak [uloc][d0 + 4 * k4];
      const f32x4 kv  = *(const f32x4*)&s_k  [uloc][d0 + 4 * k4];
      const f32x4 rav = *(const f32x4*)&s_rak[uloc][d0 + 4 * k4];
      const f32x4 rkv = *(const f32x4*)&s_rk [uloc][d0 + 4 * k4];
      const f32x4 xvA = xp[k4 * 32];
      const f32x4 xvB = xp[k4 * 32 + 16];
      const double hdA0 = __hip_atomic_load(hq + (size_t)k4 * 64,      __ATOMIC_RELAXED, AGENT);
      const double hdA1 = __hip_atomic_load(hq + (size_t)k4 * 64 + 1,  __ATOMIC_RELAXED, AGENT);
      const double hdB0 = __hip_atomic_load(hq + (size_t)k4 * 64 + 32, __ATOMIC_RELAXED, AGENT);
      const double hdB1 = __hip_atomic_load(hq + (size_t)k4 * 64 + 33, __ATOMIC_RELAXED, AGENT);
      const f32x2 ha0 = __builtin_bit_cast(f32x2, hdA0);
      const f32x2 ha1 = __builtin_bit_cast(f32x2, hdA1);
      const f32x2 hb0 = __builtin_bit_cast(f32x2, hdB0);
      const f32x2 hb1 = __builtin_bit_cast(f32x2, hdB1);
      const f32x4 hvA = {ha0.x, ha0.y, ha1.x, ha1.y};
      const f32x4 hvB = {hb0.x, hb0.y, hb1.x, hb1.y};

      f32x4 tA = (xvA * av) * hsA4;
      f32x4 tB = (xvB * av) * hsB4;
      f32x4 eA = {fexp2(tA.x), fexp2(tA.y), fexp2(tA.z), fexp2(tA.w)};
      f32x4 eB = {fexp2(tB.x), fexp2(tB.y), fexp2(tB.z), fexp2(tB.w)};
      f32x4 kxA = kv * xvA;
      f32x4 kxB = kv * xvB;
      saA += eA; laA += kxA; naA += eA * kxA;
      saB += eB; laB += kxB; naB += eB * kxB;

      f32x4 rtA = (hvA * rav) * hsA4;
      f32x4 rtB = (hvB * rav) * hsB4;
      f32x4 reA = {fexp2(rtA.x), fexp2(rtA.y), fexp2(rtA.z), fexp2(rtA.w)};
      f32x4 reB = {fexp2(rtB.x), fexp2(rtB.y), fexp2(rtB.z), fexp2(rtB.w)};
      f32x4 khA = rkv * hvA;
      f32x4 khB = rkv * hvB;
      srA += reA; lrA += khA; nrA += reA * khA;
      srB += reB; lrB += khB; nrB += reB * khB;
    }

    // horizontal collapse (4 -> 1) then reduce over 16 chunks
    float v0  = saA.x + saA.y + saA.z + saA.w;
    float v1  = naA.x + naA.y + naA.z + naA.w;
    float v2  = laA.x + laA.y + laA.z + laA.w;
    float v3  = srA.x + srA.y + srA.z + srA.w;
    float v4  = nrA.x + nrA.y + nrA.z + nrA.w;
    float v5  = lrA.x + lrA.y + lrA.z + lrA.w;
    float v6  = saB.x + saB.y + saB.z + saB.w;
    float v7  = naB.x + naB.y + naB.z + naB.w;
    float v8  = laB.x + laB.y + laB.z + laB.w;
    float v9  = srB.x + srB.y + srB.z + srB.w;
    float v10 = nrB.x + nrB.y + nrB.z + nrB.w;
    float v11 = lrB.x + lrB.y + lrB.z + lrB.w;

    v0  += __shfl_xor(v0, 16);  v0  += __shfl_xor(v0, 32);
    v1  += __shfl_xor(v1, 16);  v1  += __shfl_xor(v1, 32);
    v2  += __shfl_xor(v2, 16);  v2  += __shfl_xor(v2, 32);
    v3  += __shfl_xor(v3, 16);  v3  += __shfl_xor(v3, 32);
    v4  += __shfl_xor(v4, 16);  v4  += __shfl_xor(v4, 32);
    v5  += __shfl_xor(v5, 16);  v5  += __shfl_xor(v5, 32);
    v6  += __shfl_xor(v6, 16);  v6  += __shfl_xor(v6, 32);
    v7  += __shfl_xor(v7, 16);  v7  += __shfl_xor(v7, 32);
    v8  += __shfl_xor(v8, 16);  v8  += __shfl_xor(v8, 32);
    v9  += __shfl_xor(v9, 16);  v9  += __shfl_xor(v9, 32);
    v10 += __shfl_xor(v10, 16); v10 += __shfl_xor(v10, 32);
    v11 += __shfl_xor(v11, 16); v11 += __shfl_xor(v11, 32);

    const int w = (tid >> 6) & 3;
    if ((tid & 63) < 16) {
      red[uloc][0][w][b] = v0;   red[uloc][1][w][b] = v1;   red[uloc][2][w][b] = v2;
      red[uloc][3][w][b] = v3;   red[uloc][4][w][b] = v4;   red[uloc][5][w][b] = v5;
      red[uloc][6][w][b] = v6;   red[uloc][7][w][b] = v7;   red[uloc][8][w][b] = v8;
      red[uloc][9][w][b] = v9;   red[uloc][10][w][b] = v10; red[uloc][11][w][b] = v11;
    }
    __syncthreads();

    if (lt < 16) {
      float r0  = red[uloc][0][0][lt]  + red[uloc][0][1][lt]  + red[uloc][0][2][lt]  + red[uloc][0][3][lt];
      float r1  = red[uloc][1][0][lt]  + red[uloc][1][1][lt]  + red[uloc][1][2][lt]  + red[uloc][1][3][lt];
      float r2  = red[uloc][2][0][lt]  + red[uloc][2][1][lt]  + red[uloc][2][2][lt]  + red[uloc][2][3][lt];
      float r3  = red[uloc][3][0][lt]  + red[uloc][3][1][lt]  + red[uloc][3][2][lt]  + red[uloc][3][3][lt];
      float r4  = red[uloc][4][0][lt]  + red[uloc][4][1][lt]  + red[uloc][4][2][lt]  + red[uloc][4][3][lt];
      float r5  = red[uloc][5][0][lt]  + red[uloc][5][1][lt]  + red[uloc][5][2][lt]  + red[uloc][5][3][lt];
      float r6  = red[uloc][6][0][lt]  + red[uloc][6][1][lt]  + red[uloc][6][2][lt]  + red[uloc][6][3][lt];
      float r7  = red[uloc][7][0][lt]  + red[uloc][7][1][lt]  + red[uloc][7][2][lt]  + red[uloc][7][3][lt];
      float r8  = red[uloc][8][0][lt]  + red[uloc][8][1][lt]  + red[uloc][8][2][lt]  + red[uloc][8][3][lt];
      float r9  = red[uloc][9][0][lt]  + red[uloc][9][1][lt]  + red[uloc][9][2][lt]  + red[uloc][9][3][lt];
      float r10 = red[uloc][10][0][lt] + red[uloc][10][1][lt] + red[uloc][10][2][lt] + red[uloc][10][3][lt];
      float r11 = red[uloc][11][0][lt] + red[uloc][11][1][lt] + red[uloc][11][2][lt] + red[uloc][11][3][lt];

      float hhA = r2 + bias_u + ga * (r1 * frcp(r0));
      float zA  = hhA + r5 + gra * (r4 * frcp(r3));
      float exA = fexp2(zA * 2.8853900817779268f);   // tanh(z) = 1 - 2/(e^{2z}+1)
      float oA  = 1.0f - 2.0f * frcp(exA + 1.0f);
      float hhB = r8 + bias_u + ga * (r7 * frcp(r6));
      float zB  = hhB + r11 + gra * (r10 * frcp(r9));
      float exB = fexp2(zB * 2.8853900817779268f);
      float oB  = 1.0f - 2.0f * frcp(exB + 1.0f);

      __hip_atomic_store(&hnext[h4idx(u, lt)],      oA, __ATOMIC_RELAXED, AGENT);
      __hip_atomic_store(&hnext[h4idx(u, lt + 16)], oB, __ATOMIC_RELAXED, AGENT);
      outT[((size_t)t * NU + u) * NB + lt]      = oA;
      outT[((size_t)t * NU + u) * NB + lt + 16] = oB;
    }

    if (t != NT - 1) {
      asm volatile("s_waitcnt vmcnt(0)" ::: "memory");
      __syncthreads();   // all h-stores drained before flag publication
      if (tid == 0)
        __hip_atomic_store(&flags[blockIdx.x], (unsigned)(t + 1), __ATOMIC_RELAXED, AGENT);
      if (tid < NBLK) {
        const unsigned tgt = (unsigned)(t + 1);
        while (__hip_atomic_load(&flags[tid], __ATOMIC_RELAXED, AGENT) < tgt)
          __builtin_amdgcn_s_sleep(2);
      }
      __syncthreads();
    }
    { const float* tmp = hcur; hcur = hnext; hnext = (float*)tmp; }
  }
}

extern "C" void kernel_launch(void* const* d_in, const int* in_sizes, int n_in,
                              void* d_out, int out_size, void* d_ws, size_t ws_size,
                              hipStream_t stream) {
  const float* x    = (const float*)d_in[0];
  const float* h0   = (const float*)d_in[1];
  const float* wk   = (const float*)d_in[2];
  const float* wrk  = (const float*)d_in[3];
  const float* wak  = (const float*)d_in[4];
  const float* wrak = (const float*)d_in[5];
  const float* bias = (const float*)d_in[6];
  const float* gpa  = (const float*)d_in[7];
  const float* gpra = (const float*)d_in[8];
  float* out = (float*)d_out;

  float* x4   = (float*)d_ws;                       // 12.58 MB
  float* outT = x4 + (size_t)NT * ND * NB;          // 12.58 MB
  float* hA   = outT + (size_t)NT * NU * NB;        // 96 KB
  float* hB   = hA + NU * NB;                       // 96 KB
  unsigned int* flags = (unsigned int*)(hB + NU * NB);

  make_x4_kernel<<<dim3(NT, 6), 256, 0, stream>>>(x, x4);
  init_h4_kernel<<<(NU * NB + 255) / 256, 256, 0, stream>>>(h0, hA, flags);
  rnn_fused_kernel<<<NBLK, NTHR, 0, stream>>>(x4, wk, wrk, wak, wrak, bias, gpa, gpra,
                                              hA, hB, outT, flags);
  transpose_out_kernel<<<dim3(NT, NU / 32), 256, 0, stream>>>(outT, out);
}